// Round 5
// baseline (1657.914 us; speedup 1.0000x reference)
//
#include <hip/hip_runtime.h>
#include <math.h>

// ConvT3d(32->64,k3,s2,p1,op1) + bias + 1 + LN(C) + AvgPool2^3 + GELU, fused.
// 8 output-parity classes; pooled = mean of the 8 per-class LN'd conv values.
// Implicit GEMM per class-tap, OPERAND-SWAPPED: mfma(W, X, acc) so
// D row = channel (quad*4+reg within 16-co tile), D col = position (l15).
// Wave wv owns positions wv*16..wv*16+15; nt loop covers all 64 channels.
// => LayerNorm per position: in-lane sum over 16 (nt x reg) channel values +
//    __shfl_xor 16 / 32 across quads. No LDS round-trip, no DPP, 1 barrier.
//
// xs layout: [row=(dd*9+hy)*33+ww][ci] bf16, XOR-swizzled by 16B chunk:
// chunk' = chunk ^ (row&3). A-read offsets fold into ds_read immediates.

typedef __attribute__((ext_vector_type(8))) short short8;
typedef __attribute__((ext_vector_type(4))) float f32x4;

__device__ __forceinline__ unsigned short f2bf(float v) {
    unsigned int b = __float_as_uint(v);
    return (unsigned short)((b + 0x7fffu + ((b >> 16) & 1u)) >> 16);
}

// ---- weight prepack: wpack[tap][co][ci] bf16, tap = kd*9+kh*3+kw ----
__global__ void pack_w(const float* __restrict__ w, unsigned short* __restrict__ wp) {
    int t = blockIdx.x * 256 + threadIdx.x;
    if (t >= 27 * 64 * 32) return;
    int ci = t & 31, co = (t >> 5) & 63, tap = t >> 11;
    wp[(tap * 64 + co) * 32 + ci] = f2bf(w[(ci * 64 + co) * 27 + tap]);
}

// One conv tap: 4 W-frag loads (global, L1-hot), 4 X-frag ds_reads (one per it),
// 16 MFMA with W as the FIRST (M=co) operand, X as the SECOND (N=pos) operand.
// All register indices literal constants (no tables -> no spills).
template<int TAPC, int FOLD>
__device__ __forceinline__ void do_tap(const unsigned short* __restrict__ wpack,
    const char* xsb, const int (&aaddr)[4], int lanehw, f32x4 (&acc)[4][4])
{
    constexpr int dd = FOLD >= 99 ? 1 : 0;
    constexpr int rr = FOLD - dd * 99;
    constexpr int dh = rr >= 33 ? 1 : 0;
    constexpr int dw = rr - dh * 33;
    constexpr int XF = dd * 297 + dh * 33 + dw;   // row offset in fused xs
    constexpr int FR3 = (dd + dh + dw) & 3;       // row&3 contribution
    short8 B[4], a[4];
#pragma unroll
    for (int nt = 0; nt < 4; ++nt)
        B[nt] = *(const short8*)(wpack + TAPC * 2048 + nt * 512 + lanehw);
#pragma unroll
    for (int it = 0; it < 4; ++it)
        a[it] = *(const short8*)(xsb + aaddr[(it * 2 + FR3) & 3] + (it * 66 + XF) * 64);
#pragma unroll
    for (int it = 0; it < 4; ++it)
#pragma unroll
        for (int nt = 0; nt < 4; ++nt)
            acc[it][nt] = __builtin_amdgcn_mfma_f32_16x16x32_bf16(B[nt], a[it], acc[it][nt], 0, 0, 0);
}

__global__ __launch_bounds__(256, 2) void mfma_fused(
    const float* __restrict__ x, const unsigned short* __restrict__ wpack,
    const float* __restrict__ bias, const float* __restrict__ gamma,
    const float* __restrict__ beta, float* __restrict__ out)
{
    __shared__ unsigned short xs[594 * 32];   // [row(2dd x 9hy x 33ww)][ci] 38KB

    const int t = threadIdx.x;
    const int lane = t & 63;
    const int wv = t >> 6;                    // wave owns positions wv*16..+15
    const int l15 = lane & 15;
    const int quad = lane >> 4;

    const int b = blockIdx.x;                 // 2048 = 32n x 16dp x 4bq
    const int bq = b & 3;
    const int dp = (b >> 2) & 15;
    const int n = b >> 6;

    // ---- stage x tile (all 4 its, shared halo) -> bf16 LDS, swizzled ----
    for (int i = t; i < 2376; i += 256) {     // 33ww x 4chunk x 18(dd*9+hy)
        int ww = i % 33;
        int g = i / 33;
        int chunk = g & 3;
        int gh = g >> 2;                      // dd*9 + hy, 0..17
        int row = gh * 33 + ww;
        int dd = (gh >= 9) ? 1 : 0;
        int hy = gh - dd * 9;
        int id = dp + dd, ih = bq * 8 + hy;
        short8 v8 = (short8)0;
        if (ww < 32 && ih < 32 && id < 16) {
            const float* xp = x + (((size_t)(n * 32 + chunk * 8) * 16 + id) << 10)
                                + ih * 32 + ww;
#pragma unroll
            for (int j = 0; j < 8; ++j)
                v8[j] = (short)f2bf(xp[(size_t)j << 14]);  // ci stride 16*1024
        }
        *(short8*)((char*)xs + row * 64 + ((chunk ^ (row & 3)) << 4)) = v8;
    }
    __syncthreads();   // the ONLY barrier

    // ---- per-lane constants ----
    const int lanehw = l15 * 32 + quad * 8;
    const int base_m = (wv >> 1) * 33 + (wv & 1) * 16 + l15;   // X row for this lane
    const int lanebase = (wv >> 1) + l15;                      // base_m & 3 source
    int aaddr[4];
#pragma unroll
    for (int k = 0; k < 4; ++k)
        aaddr[k] = base_m * 64 + ((quad ^ ((lanebase + k) & 3)) << 4);

    // bias for this lane's 16 channels: c = nt*16 + quad*4 + r
    f32x4 bldq[4];
#pragma unroll
    for (int nt = 0; nt < 4; ++nt) {
        bldq[nt] = *(const f32x4*)(bias + nt * 16 + quad * 4);
#pragma unroll
        for (int r = 0; r < 4; ++r) bldq[nt][r] += 1.0f;      // + SUM_WEIGHT
    }

    float pool[4][16];
#pragma unroll
    for (int it = 0; it < 4; ++it)
#pragma unroll
        for (int j = 0; j < 16; ++j) pool[it][j] = 0.f;

    const char* xsb = (const char*)xs;

    // wave-local LN + pool accumulate for one class's acc.
    // Lane holds 16 channel values of position wv*16 + l15; sum across quads
    // via shfl_xor 16/32 completes the 64-channel stats.
    auto ln_accum = [&](f32x4 (&acc)[4][4]) {
#pragma unroll
        for (int it = 0; it < 4; ++it) {
            float v[4][4];
            float s1 = 0.f, s2 = 0.f;
#pragma unroll
            for (int nt = 0; nt < 4; ++nt)
#pragma unroll
                for (int r = 0; r < 4; ++r) {
                    float vv = acc[it][nt][r] + bldq[nt][r];
                    v[nt][r] = vv; s1 += vv; s2 += vv * vv;
                }
            s1 += __shfl_xor(s1, 16); s2 += __shfl_xor(s2, 16);
            s1 += __shfl_xor(s1, 32); s2 += __shfl_xor(s2, 32);
            float mean = s1 * 0.015625f;
            float var  = s2 * 0.015625f - mean * mean;
            float rstd = rsqrtf(var + 1e-5f);
            float mrs = mean * rstd;
#pragma unroll
            for (int nt = 0; nt < 4; ++nt)
#pragma unroll
                for (int r = 0; r < 4; ++r)
                    pool[it][nt * 4 + r] += v[nt][r] * rstd - mrs;
        }
    };

#define DT(tap, F) do_tap<tap, F>(wpack, xsb, aaddr, lanehw, acc)
    { f32x4 acc[4][4]{}; DT(13,0); ln_accum(acc); }                              // c0
    { f32x4 acc[4][4]{}; DT(12,0); DT(14,1); ln_accum(acc); }                    // c1
    { f32x4 acc[4][4]{}; DT(10,0); DT(16,33); ln_accum(acc); }                   // c2
    { f32x4 acc[4][4]{}; DT(9,0); DT(11,1); DT(15,33); DT(17,34); ln_accum(acc); } // c3
    { f32x4 acc[4][4]{}; DT(4,0); DT(22,99); ln_accum(acc); }                    // c4
    { f32x4 acc[4][4]{}; DT(3,0); DT(5,1); DT(21,99); DT(23,100); ln_accum(acc); } // c5
    { f32x4 acc[4][4]{}; DT(1,0); DT(7,33); DT(19,99); DT(25,132); ln_accum(acc); } // c6
    { f32x4 acc[4][4]{}; DT(0,0); DT(2,1); DT(6,33); DT(8,34);
                         DT(18,99); DT(20,100); DT(24,132); DT(26,133); ln_accum(acc); } // c7
#undef DT

    // ---- epilogue: /8, gamma/beta, GELU; scalar stores (64B segments/quad) ----
    f32x4 gmq[4], btq[4];
#pragma unroll
    for (int nt = 0; nt < 4; ++nt) {
        gmq[nt] = *(const f32x4*)(gamma + nt * 16 + quad * 4);
        btq[nt] = *(const f32x4*)(beta + nt * 16 + quad * 4);
    }
#pragma unroll
    for (int it = 0; it < 4; ++it) {
        const size_t pbase = ((size_t)dp << 10) + ((size_t)(bq * 8 + it * 2) << 5)
                           + wv * 16 + l15;
#pragma unroll
        for (int nt = 0; nt < 4; ++nt)
#pragma unroll
            for (int r = 0; r < 4; ++r) {
                float y = pool[it][nt * 4 + r] * 0.125f * gmq[nt][r] + btq[nt][r];
                float u = 0.7978845608028654f * (y + 0.044715f * y * y * y);
                float g = y / (1.f + __expf(-2.f * u));   // 0.5y(1+tanh(u))
                out[(((size_t)(n * 64 + nt * 16 + quad * 4 + r)) << 14) + pbase] = g;
            }
    }
}

// ---- fallback (round-0 fp32 path, direct weight reads) if ws too small ----
__global__ __launch_bounds__(256) void fused_fallback(
    const float* __restrict__ x, const float* __restrict__ w,
    const float* __restrict__ bias, const float* __restrict__ gamma,
    const float* __restrict__ beta, float* __restrict__ out)
{
    __shared__ __align__(16) float xs_lds[128 * 20];
    __shared__ float conv_lds[128 * 65];
    float* stats = xs_lds;

    const int t = threadIdx.x;
    const int b = blockIdx.x;
    const int wq = b & 1;
    const int hp = (b >> 1) & 31;
    const int dp = (b >> 6) & 15;
    const int n = b >> 10;

    for (int k = 0; k < 10; ++k) {
        int idx = t + k * 256;
        int col = idx % 20, r = idx / 20;
        int hh = r & 1, ddv = (r >> 1) & 1, ci = r >> 2;
        int iw = wq * 16 + col, ih = hp + hh, id = dp + ddv;
        float v = 0.f;
        if (col < 17 && iw < 32 && ih < 32 && id < 16)
            v = x[(((n * 32 + ci) * 16 + id) * 32 + ih) * 32 + iw];
        xs_lds[idx] = v;
    }
    __syncthreads();

    const int co = t & 63;
    const int sg = t >> 6;
    const float bco = bias[co] + 1.0f;

    for (int dd = 0; dd < 2; ++dd)
        for (int hh = 0; hh < 2; ++hh) {
            float acc[8];
#pragma unroll
            for (int j = 0; j < 8; ++j) acc[j] = 0.f;
            const int ndt = dd ? 2 : 1, nht = hh ? 2 : 1;
            for (int itp = 0; itp < ndt; ++itp) {
                const int kd = dd ? (itp ? 2 : 0) : 1;
                const int idl = dd ? itp : 0;
                for (int jt = 0; jt < nht; ++jt) {
                    const int kh = hh ? (jt ? 2 : 0) : 1;
                    const int ihl = hh ? jt : 0;
                    const int kidx = kd * 3 + kh;
#pragma unroll 4
                    for (int ci = 0; ci < 32; ++ci) {
                        const float* wp0 = w + (ci * 64 + co) * 27 + kidx * 3;
                        float w0 = wp0[0], w1 = wp0[1], w2 = wp0[2];
                        const float* xr = &xs_lds[(ci * 4 + idl * 2 + ihl) * 20 + sg * 4];
                        float4 xa = *(const float4*)xr;
                        float x4 = xr[4];
                        acc[0] += xa.x * w1;
                        acc[1] += xa.x * w0 + xa.y * w2;
                        acc[2] += xa.y * w1;
                        acc[3] += xa.y * w0 + xa.z * w2;
                        acc[4] += xa.z * w1;
                        acc[5] += xa.z * w0 + xa.w * w2;
                        acc[6] += xa.w * w1;
                        acc[7] += xa.w * w0 + x4 * w2;
                    }
                }
            }
            const int posb = (dd * 2 + hh) * 32 + sg * 8;
#pragma unroll
            for (int j = 0; j < 8; ++j)
                conv_lds[(posb + j) * 65 + co] = acc[j] + bco;
        }
    __syncthreads();

    if (t < 128) {
        float s = 0.f, ss = 0.f;
#pragma unroll 8
        for (int c = 0; c < 64; ++c) { float v = conv_lds[t * 65 + c]; s += v; ss += v * v; }
        float mean = s * (1.f / 64.f);
        float var = ss * (1.f / 64.f) - mean * mean;
        stats[t] = mean;
        stats[128 + t] = rsqrtf(var + 1e-5f);
    }
    __syncthreads();

    {
        const int wp = t & 15, cog = t >> 4;
#pragma unroll
        for (int j = 0; j < 4; ++j) {
            const int c = cog * 4 + j;
            float sum = 0.f;
#pragma unroll
            for (int pd2 = 0; pd2 < 4; ++pd2)
#pragma unroll
                for (int ww = 0; ww < 2; ++ww) {
                    const int pos = pd2 * 32 + wp * 2 + ww;
                    sum += (conv_lds[pos * 65 + c] - stats[pos]) * stats[128 + pos];
                }
            float y = sum * 0.125f * gamma[c] + beta[c];
            float u = 0.7978845608028654f * (y + 0.044715f * y * y * y);
            float g = 0.5f * y * (1.f + tanhf(u));
            out[(((n * 64 + c) * 16 + dp) * 32 + hp) * 32 + (wq * 16 + wp)] = g;
        }
    }
}

extern "C" void kernel_launch(void* const* d_in, const int* in_sizes, int n_in,
                              void* d_out, int out_size, void* d_ws, size_t ws_size,
                              hipStream_t stream) {
    const float* x = (const float*)d_in[0];
    const float* w = (const float*)d_in[1];
    const float* bias = (const float*)d_in[2];
    const float* gamma = (const float*)d_in[3];
    const float* beta = (const float*)d_in[4];
    float* out = (float*)d_out;

    const size_t need = (size_t)(27 * 64 * 32) * sizeof(unsigned short);
    if (ws_size >= need) {
        unsigned short* wpack = (unsigned short*)d_ws;
        pack_w<<<(27 * 64 * 32 + 255) / 256, 256, 0, stream>>>(w, wpack);
        mfma_fused<<<2048, 256, 0, stream>>>(x, wpack, bias, gamma, beta, out);
    } else {
        fused_fallback<<<32768, 256, 0, stream>>>(x, w, bias, gamma, beta, out);
    }
}

// Round 6
// 776.635 us; speedup vs baseline: 2.1347x; 2.1347x over previous
//
#include <hip/hip_runtime.h>
#include <math.h>

// ConvT3d(32->64,k3,s2,p1,op1) + bias + 1 + LN(C) + AvgPool2^3 + GELU, fused.
// 8 output-parity classes; pooled = mean of the 8 per-class LN'd conv values.
// Implicit GEMM per class-tap, OPERAND-SWAPPED: mfma(W, X, acc) so
// D row = channel (quad*4+reg within 16-co tile), D col = position (l15).
// Wave wv owns positions wv*16..wv*16+15; nt loop covers all 64 channels.
// LayerNorm per position: in-lane sum of 16 channel values + shfl_xor 16/32.
//
// IT-OUTER (#pragma unroll 1): per-it live state = pool[16] + acc[4] f32x4
// (32 VGPR) instead of 128 -> no scratch spills (round-5 failure mode:
// FETCH/WRITE 1.4/2.4 GB of spill traffic at 128-VGPR cap).
//
// xs layout: [row=(dd*9+hy)*33+ww][ci] bf16, XOR-swizzled by 16B chunk:
// chunk' = chunk ^ (row&3). A-read offsets fold into ds_read immediates.

typedef __attribute__((ext_vector_type(8))) short short8;
typedef __attribute__((ext_vector_type(4))) float f32x4;

__device__ __forceinline__ unsigned short f2bf(float v) {
    unsigned int b = __float_as_uint(v);
    return (unsigned short)((b + 0x7fffu + ((b >> 16) & 1u)) >> 16);
}

// ---- weight prepack: wpack[tap][co][ci] bf16, tap = kd*9+kh*3+kw ----
__global__ void pack_w(const float* __restrict__ w, unsigned short* __restrict__ wp) {
    int t = blockIdx.x * 256 + threadIdx.x;
    if (t >= 27 * 64 * 32) return;
    int ci = t & 31, co = (t >> 5) & 63, tap = t >> 11;
    wp[(tap * 64 + co) * 32 + ci] = f2bf(w[(ci * 64 + co) * 27 + tap]);
}

// One conv tap for ONE it: 4 W-frag loads (global, L1/L2-hot), 1 X-frag
// ds_read, 4 MFMA with W first (M=co), X second (N=pos). All register
// indices literal constants.
template<int TAPC, int FOLD>
__device__ __forceinline__ void do_tap(const unsigned short* __restrict__ wpack,
    const char* xsb, int a0, int a1, int a2, int a3, int lanehw, f32x4 (&acc)[4])
{
    constexpr int dd = FOLD >= 99 ? 1 : 0;
    constexpr int rr = FOLD - dd * 99;
    constexpr int dh = rr >= 33 ? 1 : 0;
    constexpr int dw = rr - dh * 33;
    constexpr int XF = dd * 297 + dh * 33 + dw;   // row offset in fused xs
    constexpr int FR3 = (dd + dh + dw) & 3;       // row&3 contribution
    const int ao = FR3 == 0 ? a0 : FR3 == 1 ? a1 : FR3 == 2 ? a2 : a3;
    short8 A = *(const short8*)(xsb + ao + XF * 64);
    short8 B[4];
#pragma unroll
    for (int nt = 0; nt < 4; ++nt)
        B[nt] = *(const short8*)(wpack + TAPC * 2048 + nt * 512 + lanehw);
#pragma unroll
    for (int nt = 0; nt < 4; ++nt)
        acc[nt] = __builtin_amdgcn_mfma_f32_16x16x32_bf16(B[nt], A, acc[nt], 0, 0, 0);
}

__global__ __launch_bounds__(256, 2) void mfma_fused(
    const float* __restrict__ x, const unsigned short* __restrict__ wpack,
    const float* __restrict__ bias, const float* __restrict__ gamma,
    const float* __restrict__ beta, float* __restrict__ out)
{
    __shared__ unsigned short xs[594 * 32];   // [row(2dd x 9hy x 33ww)][ci] 38KB

    const int t = threadIdx.x;
    const int lane = t & 63;
    const int wv = t >> 6;                    // wave owns positions wv*16..+15
    const int l15 = lane & 15;
    const int quad = lane >> 4;

    const int b = blockIdx.x;                 // 2048 = 32n x 16dp x 4bq
    const int bq = b & 3;
    const int dp = (b >> 2) & 15;
    const int n = b >> 6;

    // ---- stage x tile (all 4 its, shared halo) -> bf16 LDS, swizzled ----
    for (int i = t; i < 2376; i += 256) {     // 33ww x 4chunk x 18(dd*9+hy)
        int ww = i % 33;
        int g = i / 33;
        int chunk = g & 3;
        int gh = g >> 2;                      // dd*9 + hy, 0..17
        int row = gh * 33 + ww;
        int dd = (gh >= 9) ? 1 : 0;
        int hy = gh - dd * 9;
        int id = dp + dd, ih = bq * 8 + hy;
        short8 v8 = (short8)0;
        if (ww < 32 && ih < 32 && id < 16) {
            const float* xp = x + (((size_t)(n * 32 + chunk * 8) * 16 + id) << 10)
                                + ih * 32 + ww;
#pragma unroll
            for (int j = 0; j < 8; ++j)
                v8[j] = (short)f2bf(xp[(size_t)j << 14]);  // ci stride 16*1024
        }
        *(short8*)((char*)xs + row * 64 + ((chunk ^ (row & 3)) << 4)) = v8;
    }
    __syncthreads();   // the ONLY barrier

    // ---- per-lane constants ----
    const int lanehw = l15 * 32 + quad * 8;
    const int base_m = (wv >> 1) * 33 + (wv & 1) * 16 + l15;   // X row for this lane
    const int lanebase = (wv >> 1) + l15;                      // base_m & 3 source
    int aaddr[4];
#pragma unroll
    for (int k = 0; k < 4; ++k)
        aaddr[k] = base_m * 64 + ((quad ^ ((lanebase + k) & 3)) << 4);

    // bias for this lane's 16 channels: c = nt*16 + quad*4 + r
    f32x4 bldq[4];
#pragma unroll
    for (int nt = 0; nt < 4; ++nt) {
        bldq[nt] = *(const f32x4*)(bias + nt * 16 + quad * 4);
#pragma unroll
        for (int r = 0; r < 4; ++r) bldq[nt][r] += 1.0f;      // + SUM_WEIGHT
    }

    const char* xsb = (const char*)xs;

#pragma unroll 1
    for (int it = 0; it < 4; ++it) {
        // per-it A-frag base addresses: aaddr[(2*it+k)&3] + it*4224 bytes.
        // (2*it)&3 is 0 or 2 -> index = k ^ (2*(it&1)): literal-index selects.
        const int itoff = it * 4224;
        const bool odd = (it & 1) != 0;
        const int a0 = (odd ? aaddr[2] : aaddr[0]) + itoff;
        const int a1 = (odd ? aaddr[3] : aaddr[1]) + itoff;
        const int a2 = (odd ? aaddr[0] : aaddr[2]) + itoff;
        const int a3 = (odd ? aaddr[1] : aaddr[3]) + itoff;

        float pool[16];
#pragma unroll
        for (int j = 0; j < 16; ++j) pool[j] = 0.f;

        // wave-local LN + pool accumulate for one class (in-place in acc)
        auto ln_class = [&](f32x4 (&acc)[4]) {
            float s1 = 0.f, s2 = 0.f;
#pragma unroll
            for (int nt = 0; nt < 4; ++nt)
#pragma unroll
                for (int r = 0; r < 4; ++r) {
                    float vv = acc[nt][r] + bldq[nt][r];
                    acc[nt][r] = vv; s1 += vv; s2 += vv * vv;
                }
            s1 += __shfl_xor(s1, 16); s2 += __shfl_xor(s2, 16);
            s1 += __shfl_xor(s1, 32); s2 += __shfl_xor(s2, 32);
            float mean = s1 * 0.015625f;
            float var  = s2 * 0.015625f - mean * mean;
            float rstd = rsqrtf(var + 1e-5f);
            float mrs = mean * rstd;
#pragma unroll
            for (int nt = 0; nt < 4; ++nt)
#pragma unroll
                for (int r = 0; r < 4; ++r)
                    pool[nt * 4 + r] += acc[nt][r] * rstd - mrs;
        };

#define DT(tap, F) do_tap<tap, F>(wpack, xsb, a0, a1, a2, a3, lanehw, acc)
        { f32x4 acc[4]{}; DT(13,0); ln_class(acc); }                                 // c0
        { f32x4 acc[4]{}; DT(12,0); DT(14,1); ln_class(acc); }                       // c1
        { f32x4 acc[4]{}; DT(10,0); DT(16,33); ln_class(acc); }                      // c2
        { f32x4 acc[4]{}; DT(9,0); DT(11,1); DT(15,33); DT(17,34); ln_class(acc); }  // c3
        { f32x4 acc[4]{}; DT(4,0); DT(22,99); ln_class(acc); }                       // c4
        { f32x4 acc[4]{}; DT(3,0); DT(5,1); DT(21,99); DT(23,100); ln_class(acc); }  // c5
        { f32x4 acc[4]{}; DT(1,0); DT(7,33); DT(19,99); DT(25,132); ln_class(acc); } // c6
        { f32x4 acc[4]{}; DT(0,0); DT(2,1); DT(6,33); DT(8,34);
                          DT(18,99); DT(20,100); DT(24,132); DT(26,133); ln_class(acc); } // c7
#undef DT

        // ---- epilogue for this it: /8, gamma/beta, GELU; scalar stores ----
        const size_t pbase = ((size_t)dp << 10) + ((size_t)(bq * 8 + it * 2) << 5)
                           + wv * 16 + l15;
#pragma unroll
        for (int nt = 0; nt < 4; ++nt) {
            f32x4 gmq = *(const f32x4*)(gamma + nt * 16 + quad * 4);
            f32x4 btq = *(const f32x4*)(beta + nt * 16 + quad * 4);
#pragma unroll
            for (int r = 0; r < 4; ++r) {
                float y = pool[nt * 4 + r] * 0.125f * gmq[r] + btq[r];
                float u = 0.7978845608028654f * (y + 0.044715f * y * y * y);
                float g = y / (1.f + __expf(-2.f * u));   // 0.5y(1+tanh(u))
                out[(((size_t)(n * 64 + nt * 16 + quad * 4 + r)) << 14) + pbase] = g;
            }
        }
    }
}

// ---- fallback (round-0 fp32 path, direct weight reads) if ws too small ----
__global__ __launch_bounds__(256) void fused_fallback(
    const float* __restrict__ x, const float* __restrict__ w,
    const float* __restrict__ bias, const float* __restrict__ gamma,
    const float* __restrict__ beta, float* __restrict__ out)
{
    __shared__ __align__(16) float xs_lds[128 * 20];
    __shared__ float conv_lds[128 * 65];
    float* stats = xs_lds;

    const int t = threadIdx.x;
    const int b = blockIdx.x;
    const int wq = b & 1;
    const int hp = (b >> 1) & 31;
    const int dp = (b >> 6) & 15;
    const int n = b >> 10;

    for (int k = 0; k < 10; ++k) {
        int idx = t + k * 256;
        int col = idx % 20, r = idx / 20;
        int hh = r & 1, ddv = (r >> 1) & 1, ci = r >> 2;
        int iw = wq * 16 + col, ih = hp + hh, id = dp + ddv;
        float v = 0.f;
        if (col < 17 && iw < 32 && ih < 32 && id < 16)
            v = x[(((n * 32 + ci) * 16 + id) * 32 + ih) * 32 + iw];
        xs_lds[idx] = v;
    }
    __syncthreads();

    const int co = t & 63;
    const int sg = t >> 6;
    const float bco = bias[co] + 1.0f;

    for (int dd = 0; dd < 2; ++dd)
        for (int hh = 0; hh < 2; ++hh) {
            float acc[8];
#pragma unroll
            for (int j = 0; j < 8; ++j) acc[j] = 0.f;
            const int ndt = dd ? 2 : 1, nht = hh ? 2 : 1;
            for (int itp = 0; itp < ndt; ++itp) {
                const int kd = dd ? (itp ? 2 : 0) : 1;
                const int idl = dd ? itp : 0;
                for (int jt = 0; jt < nht; ++jt) {
                    const int kh = hh ? (jt ? 2 : 0) : 1;
                    const int ihl = hh ? jt : 0;
                    const int kidx = kd * 3 + kh;
#pragma unroll 4
                    for (int ci = 0; ci < 32; ++ci) {
                        const float* wp0 = w + (ci * 64 + co) * 27 + kidx * 3;
                        float w0 = wp0[0], w1 = wp0[1], w2 = wp0[2];
                        const float* xr = &xs_lds[(ci * 4 + idl * 2 + ihl) * 20 + sg * 4];
                        float4 xa = *(const float4*)xr;
                        float x4 = xr[4];
                        acc[0] += xa.x * w1;
                        acc[1] += xa.x * w0 + xa.y * w2;
                        acc[2] += xa.y * w1;
                        acc[3] += xa.y * w0 + xa.z * w2;
                        acc[4] += xa.z * w1;
                        acc[5] += xa.z * w0 + xa.w * w2;
                        acc[6] += xa.w * w1;
                        acc[7] += xa.w * w0 + x4 * w2;
                    }
                }
            }
            const int posb = (dd * 2 + hh) * 32 + sg * 8;
#pragma unroll
            for (int j = 0; j < 8; ++j)
                conv_lds[(posb + j) * 65 + co] = acc[j] + bco;
        }
    __syncthreads();

    if (t < 128) {
        float s = 0.f, ss = 0.f;
#pragma unroll 8
        for (int c = 0; c < 64; ++c) { float v = conv_lds[t * 65 + c]; s += v; ss += v * v; }
        float mean = s * (1.f / 64.f);
        float var = ss * (1.f / 64.f) - mean * mean;
        stats[t] = mean;
        stats[128 + t] = rsqrtf(var + 1e-5f);
    }
    __syncthreads();

    {
        const int wp = t & 15, cog = t >> 4;
#pragma unroll
        for (int j = 0; j < 4; ++j) {
            const int c = cog * 4 + j;
            float sum = 0.f;
#pragma unroll
            for (int pd2 = 0; pd2 < 4; ++pd2)
#pragma unroll
                for (int ww = 0; ww < 2; ++ww) {
                    const int pos = pd2 * 32 + wp * 2 + ww;
                    sum += (conv_lds[pos * 65 + c] - stats[pos]) * stats[128 + pos];
                }
            float y = sum * 0.125f * gamma[c] + beta[c];
            float u = 0.7978845608028654f * (y + 0.044715f * y * y * y);
            float g = 0.5f * y * (1.f + tanhf(u));
            out[(((n * 64 + c) * 16 + dp) * 32 + hp) * 32 + (wq * 16 + wp)] = g;
        }
    }
}

extern "C" void kernel_launch(void* const* d_in, const int* in_sizes, int n_in,
                              void* d_out, int out_size, void* d_ws, size_t ws_size,
                              hipStream_t stream) {
    const float* x = (const float*)d_in[0];
    const float* w = (const float*)d_in[1];
    const float* bias = (const float*)d_in[2];
    const float* gamma = (const float*)d_in[3];
    const float* beta = (const float*)d_in[4];
    float* out = (float*)d_out;

    const size_t need = (size_t)(27 * 64 * 32) * sizeof(unsigned short);
    if (ws_size >= need) {
        unsigned short* wpack = (unsigned short*)d_ws;
        pack_w<<<(27 * 64 * 32 + 255) / 256, 256, 0, stream>>>(w, wpack);
        mfma_fused<<<2048, 256, 0, stream>>>(x, wpack, bias, gamma, beta, out);
    } else {
        fused_fallback<<<32768, 256, 0, stream>>>(x, w, bias, gamma, beta, out);
    }
}